// Round 4
// baseline (397.503 us; speedup 1.0000x reference)
//
#include <hip/hip_runtime.h>
#include <math.h>

// x,y,z each (4, 256, 32, 32, 32) fp32.
// Per (b,c): S = sum over 2x2x2 windows of max(window) + total_sum/8.
// pooled[b,c] = (Sx+Sy)^2 + (Sy+Sz)^2 + (Sx+Sz)^2 ; out[b,:] = pooled/||pooled||
//
// Single fused kernel: 1024 blocks (one per bc) x 512 threads. Each block
// reduces its slice of x,y,z, writes 3 partials to ws, then ticks a per-batch
// device-scope counter; the last block of each batch (256 blocks) performs the
// 256-channel L2-normalize for that batch. Counters zeroed per call via
// hipMemsetAsync (16 B).

#define BC_TOTAL 1024          // 4 * 256
#define SLICE_ELEMS 32768      // 32*32*32

__global__ __launch_bounds__(512) void fused_kernel(
    const float* __restrict__ x,
    const float* __restrict__ y,
    const float* __restrict__ z,
    float* __restrict__ ws,
    float* __restrict__ out)
{
    const int bc = blockIdx.x;      // 0..1023
    const int b  = bc >> 8;         // batch 0..3
    const int t  = threadIdx.x;     // 0..511

    // Work item idx = t + 512*it (it=0..3): d4=idx&7, ww=(idx>>3)&15,
    // wh=(t>>7)+4*it -> base walks +8192 floats per it.
    const int off0 = (t >> 7) * 2048 + ((t >> 3) & 15) * 64 + (t & 7) * 4;

    float acc[3];

#pragma unroll
    for (int w = 0; w < 3; ++w) {
        const float* __restrict__ q =
            (w == 0 ? x : (w == 1 ? y : z)) + (size_t)bc * SLICE_ELEMS + off0;

        float a0s = 0.0f, a1s = 0.0f;
#pragma unroll
        for (int it = 0; it < 4; ++it) {
            const float* __restrict__ r = q + it * 8192;
            const float4 a0 = *reinterpret_cast<const float4*>(r);          // (h0,w0)
            const float4 a1 = *reinterpret_cast<const float4*>(r + 32);     // (h0,w1)
            const float4 a2 = *reinterpret_cast<const float4*>(r + 1024);   // (h1,w0)
            const float4 a3 = *reinterpret_cast<const float4*>(r + 1056);   // (h1,w1)

            const float mx = fmaxf(fmaxf(a0.x, a1.x), fmaxf(a2.x, a3.x));
            const float my = fmaxf(fmaxf(a0.y, a1.y), fmaxf(a2.y, a3.y));
            const float mz = fmaxf(fmaxf(a0.z, a1.z), fmaxf(a2.z, a3.z));
            const float mw = fmaxf(fmaxf(a0.w, a1.w), fmaxf(a2.w, a3.w));

            const float s = ((a0.x + a0.y) + (a0.z + a0.w))
                          + ((a1.x + a1.y) + (a1.z + a1.w))
                          + ((a2.x + a2.y) + (a2.z + a2.w))
                          + ((a3.x + a3.y) + (a3.z + a3.w));

            const float contrib = fmaxf(mx, my) + fmaxf(mz, mw) + s * 0.125f;
            if (it & 1) a1s += contrib; else a0s += contrib;
        }
        acc[w] = a0s + a1s;
    }

    // Block reduction: wave shuffle, then LDS across 8 waves.
#pragma unroll
    for (int off = 32; off > 0; off >>= 1) {
        acc[0] += __shfl_down(acc[0], off);
        acc[1] += __shfl_down(acc[1], off);
        acc[2] += __shfl_down(acc[2], off);
    }

    __shared__ float red[8][3];
    const int wave = t >> 6;
    if ((t & 63) == 0) {
        red[wave][0] = acc[0];
        red[wave][1] = acc[1];
        red[wave][2] = acc[2];
    }
    __syncthreads();
    if (t < 3) {
        float s = 0.0f;
#pragma unroll
        for (int wv = 0; wv < 8; ++wv) s += red[wv][t];
        ws[t * BC_TOTAL + bc] = s;
    }

    // ---- last-block-per-batch finalize (hipCUB pattern) ----
    __threadfence();           // release: ws stores visible device-wide
    __syncthreads();

    __shared__ int finflag;
    unsigned int* cnt = (unsigned int*)(ws + 3 * BC_TOTAL);
    if (t == 0) {
        const unsigned int old = atomicAdd(&cnt[b], 1u);
        finflag = (old == 255u) ? b : -1;
    }
    __syncthreads();
    const int fb = finflag;    // uniform across block
    if (fb < 0) return;

    __threadfence();           // acquire: see all 256 blocks' ws stores

    volatile const float* vws = (volatile const float*)ws;
    float pooled = 0.0f, sq = 0.0f;
    if (t < 256) {
        const int bc2 = fb * 256 + t;
        const float Sx = vws[bc2];
        const float Sy = vws[BC_TOTAL + bc2];
        const float Sz = vws[2 * BC_TOTAL + bc2];
        const float xy = Sx + Sy;
        const float yz = Sy + Sz;
        const float xz = Sx + Sz;
        pooled = xy * xy + yz * yz + xz * xz;
        sq = pooled * pooled;
    }
#pragma unroll
    for (int off = 32; off > 0; off >>= 1) sq += __shfl_down(sq, off);

    __shared__ float red2[8];
    if ((t & 63) == 0) red2[wave] = sq;
    __syncthreads();

    __shared__ float norm_s;
    if (t == 0) {
        float s = 0.0f;
#pragma unroll
        for (int wv = 0; wv < 8; ++wv) s += red2[wv];
        norm_s = sqrtf(s);
    }
    __syncthreads();

    if (t < 256) {
        out[fb * 256 + t] = pooled / fmaxf(norm_s, 1e-12f);
    }
}

extern "C" void kernel_launch(void* const* d_in, const int* in_sizes, int n_in,
                              void* d_out, int out_size, void* d_ws, size_t ws_size,
                              hipStream_t stream) {
    const float* x = (const float*)d_in[0];
    const float* y = (const float*)d_in[1];
    const float* z = (const float*)d_in[2];
    float* ws = (float*)d_ws;      // [3*1024] partial sums, then 4 u32 counters
    float* out = (float*)d_out;    // 1024 floats (4 x 256)

    hipMemsetAsync(ws + 3 * BC_TOTAL, 0, 4 * sizeof(unsigned int), stream);
    fused_kernel<<<BC_TOTAL, 512, 0, stream>>>(x, y, z, ws, out);
}

// Round 5
// 74.215 us; speedup vs baseline: 5.3561x; 5.3561x over previous
//
#include <hip/hip_runtime.h>
#include <math.h>

// Problem: x,y,z each (4, 256, 32, 32, 32) fp32.
// Per (b,c): S = sum over 2x2x2 windows of max(window) + total_sum/8.
// pooled[b,c] = (Sx+Sy)^2 + (Sy+Sz)^2 + (Sx+Sz)^2
// out[b,:] = pooled[b,:] / max(||pooled[b,:]||_2, 1e-12)
//
// Grid: 1024 blocks (one per bc slice) x 512 threads; each block reads all
// three inputs' slices. 1024 = 4*256 -> even block/CU schedule at any
// residency (4/2/1 blocks per CU), no partial-round tail.
//
// NOTE (R4 post-mortem): do NOT fuse the finalize via per-block
// __threadfence + atomic counter — device-scope fences from 1024 blocks
// serialize the L2s (74 -> 397 us measured). Two kernels is the fast shape.

#define BC_TOTAL 1024          // 4 * 256
#define SLICE_ELEMS 32768      // 32*32*32

__global__ __launch_bounds__(512) void pool_sum_kernel(
    const float* __restrict__ x,
    const float* __restrict__ y,
    const float* __restrict__ z,
    float* __restrict__ ws)
{
    const int bc = blockIdx.x;      // 0..1023  -> (b,c) slice
    const int t = threadIdx.x;      // 0..511

    // Work item idx = t + 512*it (it=0..3): d4 = idx&7, ww = (idx>>3)&15,
    // wh = idx>>7 = (t>>7) + 4*it. d4/ww invariant per thread; base walks
    // +8192 floats per it.
    const int off0 = (t >> 7) * 2048 + ((t >> 3) & 15) * 64 + (t & 7) * 4;

    float acc[3];

#pragma unroll
    for (int w = 0; w < 3; ++w) {
        const float* __restrict__ q =
            (w == 0 ? x : (w == 1 ? y : z)) + (size_t)bc * SLICE_ELEMS + off0;

        // Batch all 16 loads (4 work-items x 4 corners) before consuming.
        float4 v[16];
#pragma unroll
        for (int it = 0; it < 4; ++it) {
            const float* __restrict__ r = q + it * 8192;
            v[4 * it + 0] = *reinterpret_cast<const float4*>(r);          // (h0,w0)
            v[4 * it + 1] = *reinterpret_cast<const float4*>(r + 32);     // (h0,w1)
            v[4 * it + 2] = *reinterpret_cast<const float4*>(r + 1024);   // (h1,w0)
            v[4 * it + 3] = *reinterpret_cast<const float4*>(r + 1056);   // (h1,w1)
        }
        // Keep all 16 loads issued before any consumption.
        __builtin_amdgcn_sched_barrier(0);

        float a0s = 0.0f, a1s = 0.0f;
#pragma unroll
        for (int it = 0; it < 4; ++it) {
            const float4 a0 = v[4 * it + 0];
            const float4 a1 = v[4 * it + 1];
            const float4 a2 = v[4 * it + 2];
            const float4 a3 = v[4 * it + 3];

            const float mx = fmaxf(fmaxf(a0.x, a1.x), fmaxf(a2.x, a3.x));
            const float my = fmaxf(fmaxf(a0.y, a1.y), fmaxf(a2.y, a3.y));
            const float mz = fmaxf(fmaxf(a0.z, a1.z), fmaxf(a2.z, a3.z));
            const float mw = fmaxf(fmaxf(a0.w, a1.w), fmaxf(a2.w, a3.w));

            const float s = ((a0.x + a0.y) + (a0.z + a0.w))
                          + ((a1.x + a1.y) + (a1.z + a1.w))
                          + ((a2.x + a2.y) + (a2.z + a2.w))
                          + ((a3.x + a3.y) + (a3.z + a3.w));

            const float contrib = fmaxf(mx, my) + fmaxf(mz, mw) + s * 0.125f;
            if (it & 1) a1s += contrib; else a0s += contrib;
        }
        acc[w] = a0s + a1s;
    }

    // Block reduction: wave shuffle (3 values together), then LDS across 8 waves.
#pragma unroll
    for (int off = 32; off > 0; off >>= 1) {
        acc[0] += __shfl_down(acc[0], off);
        acc[1] += __shfl_down(acc[1], off);
        acc[2] += __shfl_down(acc[2], off);
    }

    __shared__ float red[8][3];
    const int wave = t >> 6;
    if ((t & 63) == 0) {
        red[wave][0] = acc[0];
        red[wave][1] = acc[1];
        red[wave][2] = acc[2];
    }
    __syncthreads();
    if (t < 3) {
        float s = 0.0f;
#pragma unroll
        for (int wv = 0; wv < 8; ++wv) s += red[wv][t];
        ws[t * BC_TOTAL + bc] = s;
    }
}

__global__ __launch_bounds__(256) void finalize_kernel(
    const float* __restrict__ ws, float* __restrict__ out)
{
    const int b = blockIdx.x;   // 0..3
    const int c = threadIdx.x;  // 0..255
    const int bc = b * 256 + c;

    const float Sx = ws[bc];
    const float Sy = ws[BC_TOTAL + bc];
    const float Sz = ws[2 * BC_TOTAL + bc];

    const float xy = Sx + Sy;
    const float yz = Sy + Sz;
    const float xz = Sx + Sz;
    const float pooled = xy * xy + yz * yz + xz * xz;

    float sq = pooled * pooled;
#pragma unroll
    for (int off = 32; off > 0; off >>= 1) sq += __shfl_down(sq, off);

    __shared__ float red[4];
    if ((c & 63) == 0) red[c >> 6] = sq;
    __syncthreads();

    __shared__ float norm_s;
    if (c == 0) norm_s = sqrtf((red[0] + red[1]) + (red[2] + red[3]));
    __syncthreads();

    const float norm = fmaxf(norm_s, 1e-12f);
    out[bc] = pooled / norm;
}

extern "C" void kernel_launch(void* const* d_in, const int* in_sizes, int n_in,
                              void* d_out, int out_size, void* d_ws, size_t ws_size,
                              hipStream_t stream) {
    const float* x = (const float*)d_in[0];
    const float* y = (const float*)d_in[1];
    const float* z = (const float*)d_in[2];
    float* ws = (float*)d_ws;      // 3 * 1024 floats of partial sums
    float* out = (float*)d_out;    // 1024 floats (4 x 256)

    pool_sum_kernel<<<BC_TOTAL, 512, 0, stream>>>(x, y, z, ws);
    finalize_kernel<<<4, 256, 0, stream>>>(ws, out);
}